// Round 1
// baseline (321.545 us; speedup 1.0000x reference)
//
#include <hip/hip_runtime.h>

#define B_    64
#define S_    256
#define H_    768
#define A_    8
#define GNUM_ 8192
#define GSZ_  64
#define E_    256
#define TOPK_ 10
#define C_    (TOPK_*GSZ_)   // 640

// ---------------------------------------------------------------------------
// Kernel 1: attention.  One block per batch b.
// Phase 1: atten[a][s] = dot(x[b,s,:], W_att[a,:]) + b_att[a]  (LDS-tiled)
// softmax over s, weights kept in LDS.
// Phase 2: out[b,a,h] = sum_s w[a][s] * x[b,s,h]   (coalesced column pass)
// ---------------------------------------------------------------------------
__global__ __launch_bounds__(256) void attn_kernel(
    const float* __restrict__ x, const float* __restrict__ Watt,
    const float* __restrict__ batt, float* __restrict__ outw)
{
    const int b = blockIdx.x;
    const int t = threadIdx.x;
    __shared__ float Wl[A_ * H_];          // 24 KB
    __shared__ __align__(16) float Xt[S_][17]; // 17.4 KB (pad 17: conflict-free)
    __shared__ float Wsm[A_][S_];          // 8 KB
    __shared__ float red[A_][4];

    for (int i = t; i < A_ * H_; i += 256) Wl[i] = Watt[i];

    const float* xb = x + (size_t)b * S_ * H_;
    float acc[A_];
#pragma unroll
    for (int a = 0; a < A_; a++) acc[a] = 0.f;

    for (int h0 = 0; h0 < H_; h0 += 16) {
        __syncthreads();   // protect Xt from previous iteration readers (and Wl 1st iter)
#pragma unroll
        for (int p = 0; p < 4; p++) {
            int fid = p * 256 + t;          // 0..1023 float4 slots
            int r = fid >> 2;               // 0..255
            int c = (fid & 3) * 4;          // 0,4,8,12
            const float4 v = *(const float4*)(xb + (size_t)r * H_ + h0 + c);
            Xt[r][c] = v.x; Xt[r][c + 1] = v.y; Xt[r][c + 2] = v.z; Xt[r][c + 3] = v.w;
        }
        __syncthreads();
#pragma unroll
        for (int h = 0; h < 16; h++) {
            float xv = Xt[t][h];
#pragma unroll
            for (int a = 0; a < A_; a++) acc[a] += xv * Wl[a * H_ + h0 + h];
        }
    }
#pragma unroll
    for (int a = 0; a < A_; a++) acc[a] += batt[a];

    const int lane = t & 63, wv = t >> 6;
    // block max per head
#pragma unroll
    for (int a = 0; a < A_; a++) {
        float v = acc[a];
#pragma unroll
        for (int off = 32; off >= 1; off >>= 1) v = fmaxf(v, __shfl_xor(v, off));
        if (lane == 0) red[a][wv] = v;
    }
    __syncthreads();
    float ex[A_];
    float mx[A_];
#pragma unroll
    for (int a = 0; a < A_; a++) {
        mx[a] = fmaxf(fmaxf(red[a][0], red[a][1]), fmaxf(red[a][2], red[a][3]));
        ex[a] = expf(acc[a] - mx[a]);
    }
    __syncthreads();   // before reusing red for sums
#pragma unroll
    for (int a = 0; a < A_; a++) {
        float v = ex[a];
#pragma unroll
        for (int off = 32; off >= 1; off >>= 1) v += __shfl_xor(v, off);
        if (lane == 0) red[a][wv] = v;
    }
    __syncthreads();
#pragma unroll
    for (int a = 0; a < A_; a++) {
        float s = red[a][0] + red[a][1] + red[a][2] + red[a][3];
        Wsm[a][t] = ex[a] / s;
    }
    __syncthreads();

    // Phase 2: thread t owns columns h = t, t+256, t+512
    float o[A_][3];
#pragma unroll
    for (int a = 0; a < A_; a++) { o[a][0] = 0.f; o[a][1] = 0.f; o[a][2] = 0.f; }
    for (int s = 0; s < S_; s++) {
        const float* xr = xb + (size_t)s * H_;
        float xv0 = xr[t], xv1 = xr[t + 256], xv2 = xr[t + 512];
#pragma unroll
        for (int a = 0; a < A_; a++) {
            float w = Wsm[a][s];
            o[a][0] += w * xv0; o[a][1] += w * xv1; o[a][2] += w * xv2;
        }
    }
    float* ob = outw + (size_t)b * A_ * H_;
#pragma unroll
    for (int a = 0; a < A_; a++) {
        ob[a * H_ + t] = o[a][0];
        ob[a * H_ + t + 256] = o[a][1];
        ob[a * H_ + t + 512] = o[a][2];
    }
}

// ---------------------------------------------------------------------------
// Kernel 2: group classifier GEMM (512x768)x(8192x768)^T with in-block
// head-max.  64x64 tile per block, BK=32, transposed LDS tiles so the inner
// loop uses float4 ds_reads.  c_out[b][g] = max_a(dot) + b_clf[g].
// ---------------------------------------------------------------------------
__global__ __launch_bounds__(256) void clf_kernel(
    const float* __restrict__ Am, const float* __restrict__ Wclf,
    const float* __restrict__ bclf, float* __restrict__ c_out)
{
    __shared__ __align__(16) float As[32][68];  // [k][r], stride 68: f4-aligned, no conflicts
    __shared__ __align__(16) float Bs[32][68];
    __shared__ float Red[16][66];
    const int t = threadIdx.x;
    const int n0 = blockIdx.x * 64;
    const int m0 = blockIdx.y * 64;
    const int ty = t >> 4, tx = t & 15;
    float acc[4][4] = {};

    for (int k0 = 0; k0 < H_; k0 += 32) {
        __syncthreads();
#pragma unroll
        for (int i = 0; i < 2; i++) {
            int fid = i * 256 + t;       // 0..511
            int r = fid >> 3;            // 0..63
            int kb = (fid & 7) * 4;      // 0..28
            float4 va = *(const float4*)(Am + (size_t)(m0 + r) * H_ + k0 + kb);
            float4 vb = *(const float4*)(Wclf + (size_t)(n0 + r) * H_ + k0 + kb);
            As[kb + 0][r] = va.x; As[kb + 1][r] = va.y; As[kb + 2][r] = va.z; As[kb + 3][r] = va.w;
            Bs[kb + 0][r] = vb.x; Bs[kb + 1][r] = vb.y; Bs[kb + 2][r] = vb.z; Bs[kb + 3][r] = vb.w;
        }
        __syncthreads();
#pragma unroll
        for (int k = 0; k < 32; k++) {
            float4 a4 = *(const float4*)&As[k][ty * 4];
            float4 b4 = *(const float4*)&Bs[k][tx * 4];
            float ar[4] = { a4.x, a4.y, a4.z, a4.w };
            float br[4] = { b4.x, b4.y, b4.z, b4.w };
#pragma unroll
            for (int i = 0; i < 4; i++)
#pragma unroll
                for (int j = 0; j < 4; j++)
                    acc[i][j] += ar[i] * br[j];
        }
    }
    // rows m0+ty*4+i: 4 rows inside one half of an 8-head group
#pragma unroll
    for (int j = 0; j < 4; j++) {
        float v = fmaxf(fmaxf(acc[0][j], acc[1][j]), fmaxf(acc[2][j], acc[3][j]));
        Red[ty][tx * 4 + j] = v;
    }
    __syncthreads();
    for (int idx = t; idx < 512; idx += 256) {
        int col = idx & 63, lb = idx >> 6;          // lb = local b (0..7)
        float v = fmaxf(Red[lb * 2][col], Red[lb * 2 + 1][col]) + bclf[n0 + col];
        c_out[(size_t)(m0 / 8 + lb) * GNUM_ + n0 + col] = v;
    }
}

// ---------------------------------------------------------------------------
// Kernel 3: encoder GEMM (512x768)x(256x768)^T + bias -> emb[512][256]
// Same tiling as clf_kernel, no head reduction.
// ---------------------------------------------------------------------------
__global__ __launch_bounds__(256) void enc_kernel(
    const float* __restrict__ Am, const float* __restrict__ Wenc,
    const float* __restrict__ benc, float* __restrict__ emb)
{
    __shared__ __align__(16) float As[32][68];
    __shared__ __align__(16) float Bs[32][68];
    const int t = threadIdx.x;
    const int n0 = blockIdx.x * 64;
    const int m0 = blockIdx.y * 64;
    const int ty = t >> 4, tx = t & 15;
    float acc[4][4] = {};

    for (int k0 = 0; k0 < H_; k0 += 32) {
        __syncthreads();
#pragma unroll
        for (int i = 0; i < 2; i++) {
            int fid = i * 256 + t;
            int r = fid >> 3;
            int kb = (fid & 7) * 4;
            float4 va = *(const float4*)(Am + (size_t)(m0 + r) * H_ + k0 + kb);
            float4 vb = *(const float4*)(Wenc + (size_t)(n0 + r) * H_ + k0 + kb);
            As[kb + 0][r] = va.x; As[kb + 1][r] = va.y; As[kb + 2][r] = va.z; As[kb + 3][r] = va.w;
            Bs[kb + 0][r] = vb.x; Bs[kb + 1][r] = vb.y; Bs[kb + 2][r] = vb.z; Bs[kb + 3][r] = vb.w;
        }
        __syncthreads();
#pragma unroll
        for (int k = 0; k < 32; k++) {
            float4 a4 = *(const float4*)&As[k][ty * 4];
            float4 b4 = *(const float4*)&Bs[k][tx * 4];
            float ar[4] = { a4.x, a4.y, a4.z, a4.w };
            float br[4] = { b4.x, b4.y, b4.z, b4.w };
#pragma unroll
            for (int i = 0; i < 4; i++)
#pragma unroll
                for (int j = 0; j < 4; j++)
                    acc[i][j] += ar[i] * br[j];
        }
    }
#pragma unroll
    for (int i = 0; i < 4; i++)
#pragma unroll
        for (int j = 0; j < 4; j++)
            emb[(size_t)(m0 + ty * 4 + i) * E_ + n0 + tx * 4 + j] =
                acc[i][j] + benc[n0 + tx * 4 + j];
}

// ---------------------------------------------------------------------------
// Kernel 4: per-row sigmoid + exact top-10 (jax tie-break: lower index wins),
// then emit candidates (as float AND int scratch) + repeated scores.
// One block per batch row; row lives in LDS.
// ---------------------------------------------------------------------------
__global__ __launch_bounds__(256) void topk_kernel(
    const float* __restrict__ c_out, const int* __restrict__ group_y,
    float* __restrict__ cand_f, float* __restrict__ gcs, int* __restrict__ cand_i)
{
    const int b = blockIdx.x;
    const int t = threadIdx.x;
    __shared__ float pr[GNUM_];   // 32 KB
    __shared__ float bv[4];
    __shared__ int   bi[4];
    __shared__ float topv[TOPK_];
    __shared__ int   topi[TOPK_];

    const float* row = c_out + (size_t)b * GNUM_;
    for (int i = t; i < GNUM_; i += 256) {
        float x = row[i];
        pr[i] = 1.f / (1.f + expf(-x));
    }
    __syncthreads();

    const int lane = t & 63, wv = t >> 6;
    for (int k = 0; k < TOPK_; k++) {
        float best = -3.f; int besti = GNUM_;
        for (int i = t; i < GNUM_; i += 256) {
            float v = pr[i];
            if (v > best || (v == best && i < besti)) { best = v; besti = i; }
        }
#pragma unroll
        for (int off = 32; off >= 1; off >>= 1) {
            float ov = __shfl_xor(best, off);
            int   oi = __shfl_xor(besti, off);
            if (ov > best || (ov == best && oi < besti)) { best = ov; besti = oi; }
        }
        if (lane == 0) { bv[wv] = best; bi[wv] = besti; }
        __syncthreads();
        if (t == 0) {
            float bb = bv[0]; int bbi = bi[0];
            for (int w = 1; w < 4; w++)
                if (bv[w] > bb || (bv[w] == bb && bi[w] < bbi)) { bb = bv[w]; bbi = bi[w]; }
            topv[k] = bb; topi[k] = bbi;
            pr[bbi] = -2.f;   // sigmoid in (0,1): safe sentinel
        }
        __syncthreads();
    }

    for (int j = t; j < C_; j += 256) {
        int k = j >> 6, slot = j & 63;
        int gi = topi[k];
        int lbl = group_y[gi * GSZ_ + slot];
        cand_f[(size_t)b * C_ + j] = (float)lbl;
        gcs[(size_t)b * C_ + j] = topv[k];
        cand_i[b * C_ + j] = lbl;
    }
}

// ---------------------------------------------------------------------------
// Kernel 5: label scoring.  l_out[b][c] = max_a dot(embed[cand[b,c]], emb[b,a,:])
// One wave per candidate (coalesced 1KB embed-row load), emb[b] staged in LDS.
// ---------------------------------------------------------------------------
__global__ __launch_bounds__(256) void score_kernel(
    const float* __restrict__ emb, const float* __restrict__ et,
    const int* __restrict__ cand, float* __restrict__ l_out)
{
    const int b = blockIdx.x;          // 64
    const int c0 = blockIdx.y * 16;    // 40 tiles of 16 candidates
    const int t = threadIdx.x, lane = t & 63, wv = t >> 6;
    __shared__ float el[A_ * E_];      // 8 KB
    for (int i = t; i < A_ * E_; i += 256) el[i] = emb[(size_t)b * A_ * E_ + i];
    __syncthreads();

    for (int q = 0; q < 4; q++) {
        int c = c0 + wv * 4 + q;
        int lbl = cand[b * C_ + c];
        const float* er = et + (size_t)lbl * E_;
        float v0 = er[lane], v1 = er[lane + 64], v2 = er[lane + 128], v3 = er[lane + 192];
        float best = -1e30f;
#pragma unroll
        for (int a = 0; a < A_; a++) {
            const float* ea = el + a * E_;
            float p = v0 * ea[lane] + v1 * ea[lane + 64] + v2 * ea[lane + 128] + v3 * ea[lane + 192];
#pragma unroll
            for (int off = 32; off >= 1; off >>= 1) p += __shfl_xor(p, off);
            best = fmaxf(best, p);
        }
        if (lane == 0) l_out[(size_t)b * C_ + c] = best;
    }
}

// ---------------------------------------------------------------------------
extern "C" void kernel_launch(void* const* d_in, const int* in_sizes, int n_in,
                              void* d_out, int out_size, void* d_ws, size_t ws_size,
                              hipStream_t stream)
{
    (void)in_sizes; (void)n_in; (void)out_size; (void)ws_size;
    const float* x    = (const float*)d_in[0];
    const float* Watt = (const float*)d_in[1];
    const float* batt = (const float*)d_in[2];
    const float* Wclf = (const float*)d_in[3];
    const float* bclf = (const float*)d_in[4];
    const float* Wenc = (const float*)d_in[5];
    const float* benc = (const float*)d_in[6];
    const float* et   = (const float*)d_in[7];
    const int*   gy   = (const int*)d_in[8];

    float* out    = (float*)d_out;
    float* c_out  = out;                        // [64][8192]
    float* l_out  = out + (size_t)B_ * GNUM_;   // [64][640]
    float* cand_f = l_out + (size_t)B_ * C_;    // [64][640] (float-encoded ints)
    float* gcs    = cand_f + (size_t)B_ * C_;   // [64][640]

    char* ws = (char*)d_ws;
    float* outw  = (float*)ws;                              // 512*768 f32 = 1.5 MB
    float* embw  = (float*)(ws + (size_t)512 * 768 * 4);    // 512*256 f32 = 512 KB
    int*   candi = (int*)(ws + (size_t)512 * 768 * 4 + (size_t)512 * 256 * 4);  // 160 KB

    attn_kernel<<<64, 256, 0, stream>>>(x, Watt, batt, outw);
    clf_kernel<<<dim3(128, 8), 256, 0, stream>>>(outw, Wclf, bclf, c_out);
    enc_kernel<<<dim3(4, 8), 256, 0, stream>>>(outw, Wenc, benc, embw);
    topk_kernel<<<64, 256, 0, stream>>>(c_out, gy, cand_f, gcs, candi);
    score_kernel<<<dim3(64, 40), 256, 0, stream>>>(embw, et, candi, l_out);
}

// Round 2
// 223.633 us; speedup vs baseline: 1.4378x; 1.4378x over previous
//
#include <hip/hip_runtime.h>

#define B_    64
#define S_    256
#define H_    768
#define A_    8
#define GNUM_ 8192
#define GSZ_  64
#define E_    256
#define TOPK_ 10
#define C_    (TOPK_*GSZ_)   // 640

// ---------------------------------------------------------------------------
// attn1: atten logits. Block (b, s-chunk of 64). 4 thread-groups split H;
// W_att read via wave-uniform scalar loads (readfirstlane'd group index).
// Writes attT[b][s][a] (s-major) to ws.
// ---------------------------------------------------------------------------
__global__ __launch_bounds__(256) void attn1_kernel(
    const float* __restrict__ x, const float* __restrict__ Watt,
    const float* __restrict__ batt, float* __restrict__ attT)
{
    const int b  = blockIdx.x;
    const int s0 = blockIdx.y * 64;
    const int t  = threadIdx.x;
    const int sl = t & 63;
    const int g  = __builtin_amdgcn_readfirstlane(t >> 6);   // wave-uniform quarter
    __shared__ float Xt[64][65];      // stride 65 -> 2-way banks (free)
    __shared__ float Pp[8][64][5];

    const float* xb = x + ((size_t)b * S_ + s0) * H_;
    float acc[A_] = {};

    for (int h0 = 0; h0 < H_; h0 += 64) {
        __syncthreads();
#pragma unroll
        for (int i = 0; i < 4; i++) {
            int fid = i * 256 + t;          // 0..1023 float4 slots
            int r = fid >> 4;               // 0..63
            int c = (fid & 15) * 4;         // 0..60
            float4 v = *(const float4*)(xb + (size_t)r * H_ + h0 + c);
            Xt[r][c] = v.x; Xt[r][c+1] = v.y; Xt[r][c+2] = v.z; Xt[r][c+3] = v.w;
        }
        __syncthreads();
        const float* wp = Watt + h0 + g * 16;    // uniform -> s_load
#pragma unroll
        for (int h = 0; h < 16; h++) {
            float xv = Xt[sl][g * 16 + h];
#pragma unroll
            for (int a = 0; a < A_; a++) acc[a] += xv * wp[a * H_ + h];
        }
    }
#pragma unroll
    for (int a = 0; a < A_; a++) Pp[a][sl][g] = acc[a];
    __syncthreads();
#pragma unroll
    for (int i = 0; i < 2; i++) {
        int idx = i * 256 + t;             // 0..511
        int a = idx >> 6, s = idx & 63;
        float v = Pp[a][s][0] + Pp[a][s][1] + Pp[a][s][2] + Pp[a][s][3] + batt[a];
        attT[(size_t)b * (S_*A_) + (size_t)(s0 + s) * A_ + a] = v;
    }
}

// ---------------------------------------------------------------------------
// smax: softmax over s per (b,a).  64 blocks.  Writes wsmT[b][s][a].
// ---------------------------------------------------------------------------
__global__ __launch_bounds__(256) void smax_kernel(
    const float* __restrict__ attT, float* __restrict__ wsmT)
{
    const int b = blockIdx.x, t = threadIdx.x;
    __shared__ float L[S_][9];
#pragma unroll
    for (int i = 0; i < 2; i++) {
        int fid = i * 256 + t;             // float4 id 0..511
        float4 v = *(const float4*)(attT + (size_t)b * (S_*A_) + (size_t)fid * 4);
        int s = fid >> 1, a0 = (fid & 1) * 4;
        L[s][a0] = v.x; L[s][a0+1] = v.y; L[s][a0+2] = v.z; L[s][a0+3] = v.w;
    }
    __syncthreads();
    const int a = t >> 5, l = t & 31;      // 8 head-groups x 32 threads
    float mx = -1e30f;
#pragma unroll
    for (int k = 0; k < 8; k++) mx = fmaxf(mx, L[l + 32*k][a]);
#pragma unroll
    for (int off = 16; off >= 1; off >>= 1) mx = fmaxf(mx, __shfl_xor(mx, off));
    float ev[8]; float sm = 0.f;
#pragma unroll
    for (int k = 0; k < 8; k++) { ev[k] = expf(L[l + 32*k][a] - mx); sm += ev[k]; }
#pragma unroll
    for (int off = 16; off >= 1; off >>= 1) sm += __shfl_xor(sm, off);
    float inv = 1.f / sm;
#pragma unroll
    for (int k = 0; k < 8; k++)
        wsmT[(size_t)b * (S_*A_) + (size_t)(l + 32*k) * A_ + a] = ev[k] * inv;
}

// ---------------------------------------------------------------------------
// attn2: out[b,a,h] = sum_s w[s][a]*x[s][h].  Block (b, h-tile 256).
// Weights via uniform-address scalar loads; x read once, coalesced.
// ---------------------------------------------------------------------------
__global__ __launch_bounds__(256) void attn2_kernel(
    const float* __restrict__ x, const float* __restrict__ wsmT,
    float* __restrict__ outw)
{
    const int b = blockIdx.x, h0 = blockIdx.y * 256, t = threadIdx.x;
    const float* xb = x + (size_t)b * S_ * H_ + h0 + t;
    const float* wr = wsmT + (size_t)b * (S_*A_);
    float o[A_] = {};
    for (int s = 0; s < S_; s += 2) {
        float xv0 = xb[(size_t)s * H_];
        float xv1 = xb[(size_t)(s + 1) * H_];
        float4 wa = *(const float4*)(wr + s * 8);
        float4 wb = *(const float4*)(wr + s * 8 + 4);
        float4 wc = *(const float4*)(wr + s * 8 + 8);
        float4 wd = *(const float4*)(wr + s * 8 + 12);
        o[0] += wa.x * xv0 + wc.x * xv1;
        o[1] += wa.y * xv0 + wc.y * xv1;
        o[2] += wa.z * xv0 + wc.z * xv1;
        o[3] += wa.w * xv0 + wc.w * xv1;
        o[4] += wb.x * xv0 + wd.x * xv1;
        o[5] += wb.y * xv0 + wd.y * xv1;
        o[6] += wb.z * xv0 + wd.z * xv1;
        o[7] += wb.w * xv0 + wd.w * xv1;
    }
    float* ob = outw + (size_t)b * (A_*H_) + h0 + t;
#pragma unroll
    for (int a = 0; a < A_; a++) ob[a * H_] = o[a];
}

// ---------------------------------------------------------------------------
// clf: (512x768)x(8192x768)^T, 128x128 tile, 8x8 micro, BK=16, reg-prefetch.
// Head-max epilogue -> c_out[b][g] = max_a + b_clf.  Grid (64,4) = 256 blocks.
// ---------------------------------------------------------------------------
__global__ __launch_bounds__(256) void clf_kernel(
    const float* __restrict__ Am, const float* __restrict__ Wclf,
    const float* __restrict__ bclf, float* __restrict__ c_out)
{
    __shared__ float smem[2][16][132];     // As=[k][r], Bs=[k][r]; 16.9 KB
    const int t = threadIdx.x;
    const int n0 = blockIdx.x * 128, m0 = blockIdx.y * 128;
    const int tx = t & 15, ty = t >> 4;
    const int r  = t >> 2;                 // 0..63
    const int c4 = (t & 3) * 4;            // 0,4,8,12
    float acc[8][8] = {};

    const float* Ap  = Am   + (size_t)(m0 + r)      * H_ + c4;
    const float* Ap2 = Am   + (size_t)(m0 + 64 + r) * H_ + c4;
    const float* Bp  = Wclf + (size_t)(n0 + r)      * H_ + c4;
    const float* Bp2 = Wclf + (size_t)(n0 + 64 + r) * H_ + c4;

    float4 pa0 = *(const float4*)(Ap);
    float4 pa1 = *(const float4*)(Ap2);
    float4 pb0 = *(const float4*)(Bp);
    float4 pb1 = *(const float4*)(Bp2);

    for (int k0 = 0; k0 < H_; k0 += 16) {
        __syncthreads();
#pragma unroll
        for (int j = 0; j < 4; j++) {
            smem[0][c4 + j][r]      = ((const float*)&pa0)[j];
            smem[0][c4 + j][64 + r] = ((const float*)&pa1)[j];
            smem[1][c4 + j][r]      = ((const float*)&pb0)[j];
            smem[1][c4 + j][64 + r] = ((const float*)&pb1)[j];
        }
        __syncthreads();
        if (k0 + 16 < H_) {                 // issue next-tile loads early
            pa0 = *(const float4*)(Ap  + k0 + 16);
            pa1 = *(const float4*)(Ap2 + k0 + 16);
            pb0 = *(const float4*)(Bp  + k0 + 16);
            pb1 = *(const float4*)(Bp2 + k0 + 16);
        }
#pragma unroll
        for (int k = 0; k < 16; k++) {
            float4 al = *(const float4*)&smem[0][k][ty * 4];
            float4 ah = *(const float4*)&smem[0][k][64 + ty * 4];
            float4 bl = *(const float4*)&smem[1][k][tx * 4];
            float4 bh = *(const float4*)&smem[1][k][64 + tx * 4];
            float ar[8] = { al.x, al.y, al.z, al.w, ah.x, ah.y, ah.z, ah.w };
            float br[8] = { bl.x, bl.y, bl.z, bl.w, bh.x, bh.y, bh.z, bh.w };
#pragma unroll
            for (int i = 0; i < 8; i++)
#pragma unroll
                for (int j = 0; j < 8; j++)
                    acc[i][j] += ar[i] * br[j];
        }
    }

    __syncthreads();
    float* Pm = (float*)smem;              // [32][130] overlay (4160 <= 4224)
#pragma unroll
    for (int jj = 0; jj < 8; jj++) {
        int cc = (jj >> 2) * 64 + tx * 4 + (jj & 3);
        float vlo = fmaxf(fmaxf(acc[0][jj], acc[1][jj]), fmaxf(acc[2][jj], acc[3][jj]));
        float vhi = fmaxf(fmaxf(acc[4][jj], acc[5][jj]), fmaxf(acc[6][jj], acc[7][jj]));
        Pm[ty * 130 + cc]        = vlo;    // rows 4ty..4ty+3
        Pm[(16 + ty) * 130 + cc] = vhi;    // rows 64+4ty..
    }
    __syncthreads();
#pragma unroll
    for (int i = 0; i < 8; i++) {
        int idx = i * 256 + t;             // 0..2047
        int gg = idx >> 7;                 // 0..15 (b-group in tile)
        int col = idx & 127;
        float v = fmaxf(Pm[(gg * 2) * 130 + col], Pm[(gg * 2 + 1) * 130 + col])
                + bclf[n0 + col];
        c_out[(size_t)(m0 / 8 + gg) * GNUM_ + n0 + col] = v;
    }
}

// ---------------------------------------------------------------------------
// enc: (512x768)x(256x768)^T + bias -> emb[512][256].  64x64 tile, 4x4 micro.
// ---------------------------------------------------------------------------
__global__ __launch_bounds__(256) void enc_kernel(
    const float* __restrict__ Am, const float* __restrict__ Wenc,
    const float* __restrict__ benc, float* __restrict__ emb)
{
    __shared__ __align__(16) float As[32][68];
    __shared__ __align__(16) float Bs[32][68];
    const int t = threadIdx.x;
    const int n0 = blockIdx.x * 64;
    const int m0 = blockIdx.y * 64;
    const int ty = t >> 4, tx = t & 15;
    float acc[4][4] = {};

    for (int k0 = 0; k0 < H_; k0 += 32) {
        __syncthreads();
#pragma unroll
        for (int i = 0; i < 2; i++) {
            int fid = i * 256 + t;
            int r = fid >> 3;
            int kb = (fid & 7) * 4;
            float4 va = *(const float4*)(Am + (size_t)(m0 + r) * H_ + k0 + kb);
            float4 vb = *(const float4*)(Wenc + (size_t)(n0 + r) * H_ + k0 + kb);
            As[kb + 0][r] = va.x; As[kb + 1][r] = va.y; As[kb + 2][r] = va.z; As[kb + 3][r] = va.w;
            Bs[kb + 0][r] = vb.x; Bs[kb + 1][r] = vb.y; Bs[kb + 2][r] = vb.z; Bs[kb + 3][r] = vb.w;
        }
        __syncthreads();
#pragma unroll
        for (int k = 0; k < 32; k++) {
            float4 a4 = *(const float4*)&As[k][ty * 4];
            float4 b4 = *(const float4*)&Bs[k][tx * 4];
            float ar[4] = { a4.x, a4.y, a4.z, a4.w };
            float br[4] = { b4.x, b4.y, b4.z, b4.w };
#pragma unroll
            for (int i = 0; i < 4; i++)
#pragma unroll
                for (int j = 0; j < 4; j++)
                    acc[i][j] += ar[i] * br[j];
        }
    }
#pragma unroll
    for (int i = 0; i < 4; i++)
#pragma unroll
        for (int j = 0; j < 4; j++)
            emb[(size_t)(m0 + ty * 4 + i) * E_ + n0 + tx * 4 + j] =
                acc[i][j] + benc[n0 + tx * 4 + j];
}

// ---------------------------------------------------------------------------
// topk: single scan with per-thread register top-10 (static compare-swap
// insertion, no dynamic indexing), then 10 block-argmax rounds.
// Tie-break identical to jax.lax.top_k: lower index wins on equal prob.
// ---------------------------------------------------------------------------
__global__ __launch_bounds__(256) void topk_kernel(
    const float* __restrict__ c_out, const int* __restrict__ gy,
    float* __restrict__ cand_f, float* __restrict__ gcs, int* __restrict__ cand_i)
{
    const int b = blockIdx.x, t = threadIdx.x;
    const int lane = t & 63, wv = t >> 6;
    __shared__ float bvv[4]; __shared__ int bii[4];
    __shared__ float topv[TOPK_]; __shared__ int topi[TOPK_];

    const float* row = c_out + (size_t)b * GNUM_;
    float lv[TOPK_]; int li[TOPK_];
#pragma unroll
    for (int k = 0; k < TOPK_; k++) { lv[k] = -1.f; li[k] = 0x7fffffff; }

    for (int i = t; i < GNUM_; i += 256) {
        float p = 1.f / (1.f + expf(-row[i]));
        if (p > lv[TOPK_ - 1]) {           // equal -> new (higher idx) drops: correct
            float cv = p; int ci = i;
#pragma unroll
            for (int k = 0; k < TOPK_; k++) {   // bubble insert, strict >
                bool sw = (cv > lv[k]);
                float tv = sw ? lv[k] : cv; int ti = sw ? li[k] : ci;
                lv[k] = sw ? cv : lv[k];    li[k] = sw ? ci : li[k];
                cv = tv; ci = ti;
            }
        }
    }

    for (int rnd = 0; rnd < TOPK_; rnd++) {
        float bv = lv[0]; int bi = li[0];
#pragma unroll
        for (int off = 32; off >= 1; off >>= 1) {
            float ov = __shfl_xor(bv, off); int oi = __shfl_xor(bi, off);
            if (ov > bv || (ov == bv && oi < bi)) { bv = ov; bi = oi; }
        }
        if (lane == 0) { bvv[wv] = bv; bii[wv] = bi; }
        __syncthreads();
        float gbv = bvv[0]; int gbi = bii[0];
#pragma unroll
        for (int w = 1; w < 4; w++) {
            float ov = bvv[w]; int oi = bii[w];
            if (ov > gbv || (ov == gbv && oi < gbi)) { gbv = ov; gbi = oi; }
        }
        if (t == 0) { topv[rnd] = gbv; topi[rnd] = gbi; }
        if (li[0] == gbi) {                 // winner thread pops (indices unique)
#pragma unroll
            for (int k = 0; k < TOPK_ - 1; k++) { lv[k] = lv[k + 1]; li[k] = li[k + 1]; }
            lv[TOPK_ - 1] = -1.f; li[TOPK_ - 1] = 0x7fffffff;
        }
        __syncthreads();
    }

    for (int j = t; j < C_; j += 256) {
        int k = j >> 6, slot = j & 63;
        int gi = topi[k];
        int lbl = gy[gi * GSZ_ + slot];
        cand_f[(size_t)b * C_ + j] = (float)lbl;
        gcs[(size_t)b * C_ + j] = topv[k];
        cand_i[b * C_ + j] = lbl;
    }
}

// ---------------------------------------------------------------------------
// score: l_out[b][c] = max_a dot(embed[cand], emb[b,a,:]).  16 lanes per
// candidate, elements at sub*4 + 64k (2-way LDS banks).  Grid (64,10).
// ---------------------------------------------------------------------------
__global__ __launch_bounds__(256) void score_kernel(
    const float* __restrict__ embw, const float* __restrict__ et,
    const int* __restrict__ cand, float* __restrict__ l_out)
{
    const int b = blockIdx.x, c00 = blockIdx.y * 64, t = threadIdx.x;
    __shared__ float el[A_ * E_];          // 8 KB
#pragma unroll
    for (int i = 0; i < 2; i++) {
        int fid = i * 256 + t;
        *(float4*)&el[fid * 4] = *(const float4*)(embw + (size_t)b * (A_*E_) + fid * 4);
    }
    __syncthreads();
    const int lane = t & 63, wv = t >> 6, q = lane >> 4, sub = lane & 15;

    for (int it = 0; it < 4; it++) {
        int c = c00 + it * 16 + wv * 4 + q;
        int lbl = cand[b * C_ + c];
        const float* er = et + (size_t)lbl * E_ + sub * 4;
        float4 v0 = *(const float4*)(er);
        float4 v1 = *(const float4*)(er + 64);
        float4 v2 = *(const float4*)(er + 128);
        float4 v3 = *(const float4*)(er + 192);
        float best = -1e30f;
#pragma unroll
        for (int a = 0; a < A_; a++) {
            const float* ep = el + a * E_ + sub * 4;
            float4 w0 = *(const float4*)(ep);
            float4 w1 = *(const float4*)(ep + 64);
            float4 w2 = *(const float4*)(ep + 128);
            float4 w3 = *(const float4*)(ep + 192);
            float p = v0.x*w0.x + v0.y*w0.y + v0.z*w0.z + v0.w*w0.w
                    + v1.x*w1.x + v1.y*w1.y + v1.z*w1.z + v1.w*w1.w
                    + v2.x*w2.x + v2.y*w2.y + v2.z*w2.z + v2.w*w2.w
                    + v3.x*w3.x + v3.y*w3.y + v3.z*w3.z + v3.w*w3.w;
#pragma unroll
            for (int off = 8; off >= 1; off >>= 1) p += __shfl_xor(p, off);
            best = fmaxf(best, p);
        }
        if (sub == 0) l_out[(size_t)b * C_ + c] = best;
    }
}

// ---------------------------------------------------------------------------
extern "C" void kernel_launch(void* const* d_in, const int* in_sizes, int n_in,
                              void* d_out, int out_size, void* d_ws, size_t ws_size,
                              hipStream_t stream)
{
    (void)in_sizes; (void)n_in; (void)out_size; (void)ws_size;
    const float* x    = (const float*)d_in[0];
    const float* Watt = (const float*)d_in[1];
    const float* batt = (const float*)d_in[2];
    const float* Wclf = (const float*)d_in[3];
    const float* bclf = (const float*)d_in[4];
    const float* Wenc = (const float*)d_in[5];
    const float* benc = (const float*)d_in[6];
    const float* et   = (const float*)d_in[7];
    const int*   gy   = (const int*)d_in[8];

    float* out    = (float*)d_out;
    float* c_out  = out;                        // [64][8192]
    float* l_out  = out + (size_t)B_ * GNUM_;   // [64][640]
    float* cand_f = l_out + (size_t)B_ * C_;    // [64][640]
    float* gcs    = cand_f + (size_t)B_ * C_;   // [64][640]

    char* ws = (char*)d_ws;
    float* attT  = (float*)ws;                                   // 512 KB
    float* wsmT  = (float*)(ws + (size_t)(512 << 10));           // 512 KB
    float* outw  = (float*)(ws + (size_t)(1024 << 10));          // 1.5 MB
    float* embw  = (float*)(ws + (size_t)(2560 << 10));          // 512 KB
    int*   candi = (int*)  (ws + (size_t)(3072 << 10));          // 160 KB

    attn1_kernel<<<dim3(B_, 4), 256, 0, stream>>>(x, Watt, batt, attT);
    smax_kernel<<<B_, 256, 0, stream>>>(attT, wsmT);
    attn2_kernel<<<dim3(B_, 3), 256, 0, stream>>>(x, wsmT, outw);
    clf_kernel<<<dim3(64, 4), 256, 0, stream>>>(outw, Wclf, bclf, c_out);
    enc_kernel<<<dim3(4, 8), 256, 0, stream>>>(outw, Wenc, benc, embw);
    topk_kernel<<<B_, 256, 0, stream>>>(c_out, gy, cand_f, gcs, candi);
    score_kernel<<<dim3(B_, 10), 256, 0, stream>>>(embw, et, candi, l_out);
}

// Round 3
// 214.194 us; speedup vs baseline: 1.5012x; 1.0441x over previous
//
#include <hip/hip_runtime.h>

#define B_    64
#define S_    256
#define H_    768
#define A_    8
#define GNUM_ 8192
#define GSZ_  64
#define E_    256
#define TOPK_ 10
#define C_    (TOPK_*GSZ_)   // 640
#define BROWS (GNUM_ + E_)   // 8448 combined W_clf ++ W_enc rows

typedef short  bf16x8 __attribute__((ext_vector_type(8)));
typedef float  f32x4  __attribute__((ext_vector_type(4)));

__device__ __forceinline__ ushort f2bf(float x) {
    union { float f; unsigned u; } c; c.f = x;
    unsigned r = c.u + 0x7fff + ((c.u >> 16) & 1);   // round-to-nearest-even
    return (ushort)(r >> 16);
}
__device__ __forceinline__ float bf2f(ushort h) {
    union { float f; unsigned u; } c; c.u = ((unsigned)h) << 16;
    return c.f;
}

// ---------------------------------------------------------------------------
// split: W_clf (8192x768) ++ W_enc (256x768) f32 -> Bh/Bl bf16 [8448][768]
// ---------------------------------------------------------------------------
__global__ __launch_bounds__(256) void split_kernel(
    const float* __restrict__ Wclf, const float* __restrict__ Wenc,
    ushort* __restrict__ Bh, ushort* __restrict__ Bl)
{
    size_t i = ((size_t)blockIdx.x * 256 + threadIdx.x) * 4;
    const size_t clfN = (size_t)GNUM_ * H_;
    const float* src = (i < clfN) ? (Wclf + i) : (Wenc + (i - clfN));
    float4 v = *(const float4*)src;
    ushort4 h, l;
    h.x = f2bf(v.x); l.x = f2bf(v.x - bf2f(h.x));
    h.y = f2bf(v.y); l.y = f2bf(v.y - bf2f(h.y));
    h.z = f2bf(v.z); l.z = f2bf(v.z - bf2f(h.z));
    h.w = f2bf(v.w); l.w = f2bf(v.w - bf2f(h.w));
    *(ushort4*)(Bh + i) = h;
    *(ushort4*)(Bl + i) = l;
}

// ---------------------------------------------------------------------------
// attn1: atten logits.  Block (b, s-chunk of 64).  Writes attT[b][s][a].
// ---------------------------------------------------------------------------
__global__ __launch_bounds__(256) void attn1_kernel(
    const float* __restrict__ x, const float* __restrict__ Watt,
    const float* __restrict__ batt, float* __restrict__ attT)
{
    const int b  = blockIdx.x;
    const int s0 = blockIdx.y * 64;
    const int t  = threadIdx.x;
    const int sl = t & 63;
    const int g  = __builtin_amdgcn_readfirstlane(t >> 6);
    __shared__ float Xt[64][65];
    __shared__ float Pp[8][64][5];

    const float* xb = x + ((size_t)b * S_ + s0) * H_;
    float acc[A_] = {};

    for (int h0 = 0; h0 < H_; h0 += 64) {
        __syncthreads();
#pragma unroll
        for (int i = 0; i < 4; i++) {
            int fid = i * 256 + t;
            int r = fid >> 4;
            int c = (fid & 15) * 4;
            float4 v = *(const float4*)(xb + (size_t)r * H_ + h0 + c);
            Xt[r][c] = v.x; Xt[r][c+1] = v.y; Xt[r][c+2] = v.z; Xt[r][c+3] = v.w;
        }
        __syncthreads();
        const float* wp = Watt + h0 + g * 16;
#pragma unroll
        for (int h = 0; h < 16; h++) {
            float xv = Xt[sl][g * 16 + h];
#pragma unroll
            for (int a = 0; a < A_; a++) acc[a] += xv * wp[a * H_ + h];
        }
    }
#pragma unroll
    for (int a = 0; a < A_; a++) Pp[a][sl][g] = acc[a];
    __syncthreads();
#pragma unroll
    for (int i = 0; i < 2; i++) {
        int idx = i * 256 + t;
        int a = idx >> 6, s = idx & 63;
        float v = Pp[a][s][0] + Pp[a][s][1] + Pp[a][s][2] + Pp[a][s][3] + batt[a];
        attT[(size_t)b * (S_*A_) + (size_t)(s0 + s) * A_ + a] = v;
    }
}

// ---------------------------------------------------------------------------
// smax: softmax over s per (b,a).  Writes wsmT[b][s][a].
// ---------------------------------------------------------------------------
__global__ __launch_bounds__(256) void smax_kernel(
    const float* __restrict__ attT, float* __restrict__ wsmT)
{
    const int b = blockIdx.x, t = threadIdx.x;
    __shared__ float L[S_][9];
#pragma unroll
    for (int i = 0; i < 2; i++) {
        int fid = i * 256 + t;
        float4 v = *(const float4*)(attT + (size_t)b * (S_*A_) + (size_t)fid * 4);
        int s = fid >> 1, a0 = (fid & 1) * 4;
        L[s][a0] = v.x; L[s][a0+1] = v.y; L[s][a0+2] = v.z; L[s][a0+3] = v.w;
    }
    __syncthreads();
    const int a = t >> 5, l = t & 31;
    float mx = -1e30f;
#pragma unroll
    for (int k = 0; k < 8; k++) mx = fmaxf(mx, L[l + 32*k][a]);
#pragma unroll
    for (int off = 16; off >= 1; off >>= 1) mx = fmaxf(mx, __shfl_xor(mx, off));
    float ev[8]; float sm = 0.f;
#pragma unroll
    for (int k = 0; k < 8; k++) { ev[k] = expf(L[l + 32*k][a] - mx); sm += ev[k]; }
#pragma unroll
    for (int off = 16; off >= 1; off >>= 1) sm += __shfl_xor(sm, off);
    float inv = 1.f / sm;
#pragma unroll
    for (int k = 0; k < 8; k++)
        wsmT[(size_t)b * (S_*A_) + (size_t)(l + 32*k) * A_ + a] = ev[k] * inv;
}

// ---------------------------------------------------------------------------
// attn2: out[b,a,h] = sum_s w[s][a]*x[s][h]; emits A pre-split to bf16 hi/lo.
// Row layout: Ah/Al[(b*8+a)][h], 768-stride.
// ---------------------------------------------------------------------------
__global__ __launch_bounds__(256) void attn2_kernel(
    const float* __restrict__ x, const float* __restrict__ wsmT,
    ushort* __restrict__ Ah, ushort* __restrict__ Al)
{
    const int b = blockIdx.x, h0 = blockIdx.y * 256, t = threadIdx.x;
    const float* xb = x + (size_t)b * S_ * H_ + h0 + t;
    const float* wr = wsmT + (size_t)b * (S_*A_);
    float o[A_] = {};
    for (int s = 0; s < S_; s += 2) {
        float xv0 = xb[(size_t)s * H_];
        float xv1 = xb[(size_t)(s + 1) * H_];
        float4 wa = *(const float4*)(wr + s * 8);
        float4 wb = *(const float4*)(wr + s * 8 + 4);
        float4 wc = *(const float4*)(wr + s * 8 + 8);
        float4 wd = *(const float4*)(wr + s * 8 + 12);
        o[0] += wa.x * xv0 + wc.x * xv1;
        o[1] += wa.y * xv0 + wc.y * xv1;
        o[2] += wa.z * xv0 + wc.z * xv1;
        o[3] += wa.w * xv0 + wc.w * xv1;
        o[4] += wb.x * xv0 + wd.x * xv1;
        o[5] += wb.y * xv0 + wd.y * xv1;
        o[6] += wb.z * xv0 + wd.z * xv1;
        o[7] += wb.w * xv0 + wd.w * xv1;
    }
#pragma unroll
    for (int a = 0; a < A_; a++) {
        float v = o[a];
        ushort hi = f2bf(v);
        ushort lo = f2bf(v - bf2f(hi));
        size_t off = (size_t)(b * 8 + a) * H_ + h0 + t;
        Ah[off] = hi; Al[off] = lo;
    }
}

// ---------------------------------------------------------------------------
// gemm: C = A(512x768) x B^T(8448x768) in bf16x3 MFMA (AhBh + AlBh + AhBl).
// 128x128 tile, BK=32, reg->LDS double-buffer, XOR-swizzled LDS, XCD-aware
// block swizzle (4 m-blocks of a B-panel co-resident on one XCD).
// n0 <  8192: head-max epilogue -> c_out[b][g] = max_a + bclf
// n0 >= 8192: plain epilogue   -> emb[m][n-8192] = acc + benc
// ---------------------------------------------------------------------------
__global__ __launch_bounds__(256, 1) void gemm_mfma_kernel(
    const ushort* __restrict__ Ah, const ushort* __restrict__ Al,
    const ushort* __restrict__ Bh, const ushort* __restrict__ Bl,
    const float* __restrict__ bclf, const float* __restrict__ benc,
    float* __restrict__ c_out, float* __restrict__ emb)
{
    // XCD-bijective swizzle: panel p and all 4 m-blocks share f%8 (one XCD).
    const int f = blockIdx.x;
    const int xcd = f & 7, s = f >> 3;
    const int p = xcd + 8 * (s >> 2);          // B panel 0..65
    const int m = s & 3;                       // m-block 0..3
    if (p >= BROWS / 128) return;
    const int n0 = p * 128, m0 = m * 128;

    __shared__ __align__(16) ushort lds[2][4][128 * 32];   // 64 KB
    const int t = threadIdx.x;
    const int w = t >> 6, l = t & 63;
    const int mq = (w & 1) * 64, nq = (w >> 1) * 64;

    // staging: thread t handles rows srow, srow+64 at k-chunk skc (8 bf16)
    const int srow = t >> 2, skc = t & 3;
    const int wr_idx = ((srow * 32 + skc * 8) ^ ((srow & 7) << 3));
    const ushort* base0 = Ah + (size_t)m0 * H_;
    const ushort* base1 = Al + (size_t)m0 * H_;
    const ushort* base2 = Bh + (size_t)n0 * H_;
    const ushort* base3 = Bl + (size_t)n0 * H_;

    uint4 st[4][2];
    auto loadk = [&](int k0) {
        size_t o0 = (size_t)srow * H_ + k0 + skc * 8;
        size_t o1 = o0 + (size_t)64 * H_;
        st[0][0] = *(const uint4*)(base0 + o0);  st[0][1] = *(const uint4*)(base0 + o1);
        st[1][0] = *(const uint4*)(base1 + o0);  st[1][1] = *(const uint4*)(base1 + o1);
        st[2][0] = *(const uint4*)(base2 + o0);  st[2][1] = *(const uint4*)(base2 + o1);
        st[3][0] = *(const uint4*)(base3 + o0);  st[3][1] = *(const uint4*)(base3 + o1);
    };

    f32x4 acc[4][4] = {};
    loadk(0);
    const int kc = l >> 4, lr = l & 15;

    for (int kt = 0; kt < H_ / 32; ++kt) {
        ushort* bufp = &lds[kt & 1][0][0];
#pragma unroll
        for (int xx = 0; xx < 4; xx++) {
            *(uint4*)(bufp + xx * 4096 + wr_idx)        = st[xx][0];
            *(uint4*)(bufp + xx * 4096 + 2048 + wr_idx) = st[xx][1];
        }
        __syncthreads();
        if (kt + 1 < H_ / 32) loadk((kt + 1) * 32);

        bf16x8 fah[4], fal[4], fbh[4], fbl[4];
#pragma unroll
        for (int mt = 0; mt < 4; mt++) {
            int r = mq + mt * 16 + lr;
            int idx = ((r * 32 + kc * 8) ^ ((r & 7) << 3));
            fah[mt] = *(const bf16x8*)(bufp + idx);
            fal[mt] = *(const bf16x8*)(bufp + 4096 + idx);
        }
#pragma unroll
        for (int nt = 0; nt < 4; nt++) {
            int r = nq + nt * 16 + lr;
            int idx = ((r * 32 + kc * 8) ^ ((r & 7) << 3));
            fbh[nt] = *(const bf16x8*)(bufp + 2 * 4096 + idx);
            fbl[nt] = *(const bf16x8*)(bufp + 3 * 4096 + idx);
        }
#pragma unroll
        for (int mt = 0; mt < 4; mt++)
#pragma unroll
            for (int nt = 0; nt < 4; nt++) {
                acc[mt][nt] = __builtin_amdgcn_mfma_f32_16x16x32_bf16(fah[mt], fbh[nt], acc[mt][nt], 0, 0, 0);
                acc[mt][nt] = __builtin_amdgcn_mfma_f32_16x16x32_bf16(fal[mt], fbh[nt], acc[mt][nt], 0, 0, 0);
                acc[mt][nt] = __builtin_amdgcn_mfma_f32_16x16x32_bf16(fah[mt], fbl[nt], acc[mt][nt], 0, 0, 0);
            }
    }

    const int q = l >> 4;
    if (n0 < GNUM_) {
#pragma unroll
        for (int mt = 0; mt < 4; mt++)
#pragma unroll
            for (int nt = 0; nt < 4; nt++) {
                f32x4 a = acc[mt][nt];
                float v = fmaxf(fmaxf(a[0], a[1]), fmaxf(a[2], a[3]));
                v = fmaxf(v, __shfl_xor(v, 16));
                if ((q & 1) == 0) {
                    int mg = m0 + mq + mt * 16 + (q >> 1) * 8;
                    int n  = n0 + nq + nt * 16 + lr;
                    c_out[(size_t)(mg >> 3) * GNUM_ + n] = v + bclf[n];
                }
            }
    } else {
#pragma unroll
        for (int mt = 0; mt < 4; mt++)
#pragma unroll
            for (int nt = 0; nt < 4; nt++) {
                int n = n0 - GNUM_ + nq + nt * 16 + lr;
                float bn = benc[n];
#pragma unroll
                for (int r2 = 0; r2 < 4; r2++) {
                    int mg = m0 + mq + mt * 16 + q * 4 + r2;
                    emb[(size_t)mg * E_ + n] = acc[mt][nt][r2] + bn;
                }
            }
    }
}

// ---------------------------------------------------------------------------
// topk: single scan, per-thread register top-10, 10 block-argmax rounds.
// Tie-break identical to jax.lax.top_k (lower index wins).
// ---------------------------------------------------------------------------
__global__ __launch_bounds__(256) void topk_kernel(
    const float* __restrict__ c_out, const int* __restrict__ gy,
    float* __restrict__ cand_f, float* __restrict__ gcs, int* __restrict__ cand_i)
{
    const int b = blockIdx.x, t = threadIdx.x;
    const int lane = t & 63, wv = t >> 6;
    __shared__ float bvv[4]; __shared__ int bii[4];
    __shared__ float topv[TOPK_]; __shared__ int topi[TOPK_];

    const float* row = c_out + (size_t)b * GNUM_;
    float lv[TOPK_]; int li[TOPK_];
#pragma unroll
    for (int k = 0; k < TOPK_; k++) { lv[k] = -1.f; li[k] = 0x7fffffff; }

    for (int i = t; i < GNUM_; i += 256) {
        float p = 1.f / (1.f + expf(-row[i]));
        if (p > lv[TOPK_ - 1]) {
            float cv = p; int ci = i;
#pragma unroll
            for (int k = 0; k < TOPK_; k++) {
                bool sw = (cv > lv[k]);
                float tv = sw ? lv[k] : cv; int ti = sw ? li[k] : ci;
                lv[k] = sw ? cv : lv[k];    li[k] = sw ? ci : li[k];
                cv = tv; ci = ti;
            }
        }
    }

    for (int rnd = 0; rnd < TOPK_; rnd++) {
        float bv = lv[0]; int bi = li[0];
#pragma unroll
        for (int off = 32; off >= 1; off >>= 1) {
            float ov = __shfl_xor(bv, off); int oi = __shfl_xor(bi, off);
            if (ov > bv || (ov == bv && oi < bi)) { bv = ov; bi = oi; }
        }
        if (lane == 0) { bvv[wv] = bv; bii[wv] = bi; }
        __syncthreads();
        float gbv = bvv[0]; int gbi = bii[0];
#pragma unroll
        for (int w = 1; w < 4; w++) {
            float ov = bvv[w]; int oi = bii[w];
            if (ov > gbv || (ov == gbv && oi < gbi)) { gbv = ov; gbi = oi; }
        }
        if (t == 0) { topv[rnd] = gbv; topi[rnd] = gbi; }
        if (li[0] == gbi) {
#pragma unroll
            for (int k = 0; k < TOPK_ - 1; k++) { lv[k] = lv[k + 1]; li[k] = li[k + 1]; }
            lv[TOPK_ - 1] = -1.f; li[TOPK_ - 1] = 0x7fffffff;
        }
        __syncthreads();
    }

    for (int j = t; j < C_; j += 256) {
        int k = j >> 6, slot = j & 63;
        int gi = topi[k];
        int lbl = gy[gi * GSZ_ + slot];
        cand_f[(size_t)b * C_ + j] = (float)lbl;
        gcs[(size_t)b * C_ + j] = topv[k];
        cand_i[b * C_ + j] = lbl;
    }
}

// ---------------------------------------------------------------------------
// score: l_out[b][c] = max_a dot(embed[cand], emb[b,a,:]).  16 lanes/cand.
// ---------------------------------------------------------------------------
__global__ __launch_bounds__(256) void score_kernel(
    const float* __restrict__ embw, const float* __restrict__ et,
    const int* __restrict__ cand, float* __restrict__ l_out)
{
    const int b = blockIdx.x, c00 = blockIdx.y * 64, t = threadIdx.x;
    __shared__ float el[A_ * E_];
#pragma unroll
    for (int i = 0; i < 2; i++) {
        int fid = i * 256 + t;
        *(float4*)&el[fid * 4] = *(const float4*)(embw + (size_t)b * (A_*E_) + fid * 4);
    }
    __syncthreads();
    const int lane = t & 63, wv = t >> 6, q = lane >> 4, sub = lane & 15;

    for (int it = 0; it < 4; it++) {
        int c = c00 + it * 16 + wv * 4 + q;
        int lbl = cand[b * C_ + c];
        const float* er = et + (size_t)lbl * E_ + sub * 4;
        float4 v0 = *(const float4*)(er);
        float4 v1 = *(const float4*)(er + 64);
        float4 v2 = *(const float4*)(er + 128);
        float4 v3 = *(const float4*)(er + 192);
        float best = -1e30f;
#pragma unroll
        for (int a = 0; a < A_; a++) {
            const float* ep = el + a * E_ + sub * 4;
            float4 w0 = *(const float4*)(ep);
            float4 w1 = *(const float4*)(ep + 64);
            float4 w2 = *(const float4*)(ep + 128);
            float4 w3 = *(const float4*)(ep + 192);
            float p = v0.x*w0.x + v0.y*w0.y + v0.z*w0.z + v0.w*w0.w
                    + v1.x*w1.x + v1.y*w1.y + v1.z*w1.z + v1.w*w1.w
                    + v2.x*w2.x + v2.y*w2.y + v2.z*w2.z + v2.w*w2.w
                    + v3.x*w3.x + v3.y*w3.y + v3.z*w3.z + v3.w*w3.w;
#pragma unroll
            for (int off = 8; off >= 1; off >>= 1) p += __shfl_xor(p, off);
            best = fmaxf(best, p);
        }
        if (sub == 0) l_out[(size_t)b * C_ + c] = best;
    }
}

// ---------------------------------------------------------------------------
extern "C" void kernel_launch(void* const* d_in, const int* in_sizes, int n_in,
                              void* d_out, int out_size, void* d_ws, size_t ws_size,
                              hipStream_t stream)
{
    (void)in_sizes; (void)n_in; (void)out_size; (void)ws_size;
    const float* x    = (const float*)d_in[0];
    const float* Watt = (const float*)d_in[1];
    const float* batt = (const float*)d_in[2];
    const float* Wclf = (const float*)d_in[3];
    const float* bclf = (const float*)d_in[4];
    const float* Wenc = (const float*)d_in[5];
    const float* benc = (const float*)d_in[6];
    const float* et   = (const float*)d_in[7];
    const int*   gy   = (const int*)d_in[8];

    float* out    = (float*)d_out;
    float* c_out  = out;                        // [64][8192]
    float* l_out  = out + (size_t)B_ * GNUM_;   // [64][640]
    float* cand_f = l_out + (size_t)B_ * C_;    // [64][640]
    float* gcs    = cand_f + (size_t)B_ * C_;   // [64][640]

    char* ws = (char*)d_ws;
    float*  attT  = (float*) (ws);                      // 512 KB
    float*  wsmT  = (float*) (ws + 524288);             // 512 KB
    float*  embw  = (float*) (ws + 1048576);            // 512 KB
    int*    candi = (int*)   (ws + 1572864);            // 160 KB
    ushort* Ahw   = (ushort*)(ws + 1769472);            // 768 KB
    ushort* Alw   = (ushort*)(ws + 2555904);            // 768 KB
    ushort* Bhw   = (ushort*)(ws + 3342336);            // 12.97 MB
    ushort* Blw   = (ushort*)(ws + 16318464);           // 12.97 MB

    split_kernel<<<(BROWS * H_) / 1024, 256, 0, stream>>>(Wclf, Wenc, Bhw, Blw);
    attn1_kernel<<<dim3(B_, 4), 256, 0, stream>>>(x, Watt, batt, attT);
    smax_kernel<<<B_, 256, 0, stream>>>(attT, wsmT);
    attn2_kernel<<<dim3(B_, 3), 256, 0, stream>>>(x, wsmT, Ahw, Alw);
    gemm_mfma_kernel<<<288, 256, 0, stream>>>(Ahw, Alw, Bhw, Blw, bclf, benc, c_out, embw);
    topk_kernel<<<B_, 256, 0, stream>>>(c_out, gy, cand_f, gcs, candi);
    score_kernel<<<dim3(B_, 10), 256, 0, stream>>>(embw, et, candi, l_out);
}

// Round 4
// 153.867 us; speedup vs baseline: 2.0898x; 1.3921x over previous
//
#include <hip/hip_runtime.h>

#define B_    64
#define S_    256
#define H_    768
#define A_    8
#define GNUM_ 8192
#define GSZ_  64
#define E_    256
#define TOPK_ 10
#define C_    (TOPK_*GSZ_)   // 640
#define BROWS (GNUM_ + E_)   // 8448

typedef short  bf16x8 __attribute__((ext_vector_type(8)));
typedef float  f32x4  __attribute__((ext_vector_type(4)));

__device__ __forceinline__ ushort f2bf(float x) {
    union { float f; unsigned u; } c; c.f = x;
    unsigned r = c.u + 0x7fff + ((c.u >> 16) & 1);   // RNE
    return (ushort)(r >> 16);
}
__device__ __forceinline__ float bf2f(ushort h) {
    union { float f; unsigned u; } c; c.u = ((unsigned)h) << 16;
    return c.f;
}
__device__ __forceinline__ float asf(unsigned u) {
    union { unsigned u; float f; } c; c.u = u; return c.f;
}
// pack 2 f32 -> 2 bf16 (RNE), word = (bf16(b)<<16)|bf16(a)
__device__ __forceinline__ unsigned cvt_pk_bf16(float a, float b) {
    unsigned r;
    asm("v_cvt_pk_bf16_f32 %0, %1, %2" : "=v"(r) : "v"(a), "v"(b));
    return r;
}

// ---------------------------------------------------------------------------
// attn1: atten logits + bias.  Block (b, s-chunk of 64).  -> attT[b][s][a]
// ---------------------------------------------------------------------------
__global__ __launch_bounds__(256) void attn1_kernel(
    const float* __restrict__ x, const float* __restrict__ Watt,
    const float* __restrict__ batt, float* __restrict__ attT)
{
    const int b  = blockIdx.x;
    const int s0 = blockIdx.y * 64;
    const int t  = threadIdx.x;
    const int sl = t & 63;
    const int g  = __builtin_amdgcn_readfirstlane(t >> 6);
    __shared__ float Xt[64][65];
    __shared__ float Pp[8][64][5];

    const float* xb = x + ((size_t)b * S_ + s0) * H_;
    float acc[A_] = {};

    for (int h0 = 0; h0 < H_; h0 += 64) {
        __syncthreads();
#pragma unroll
        for (int i = 0; i < 4; i++) {
            int fid = i * 256 + t;
            int r = fid >> 4;
            int c = (fid & 15) * 4;
            float4 v = *(const float4*)(xb + (size_t)r * H_ + h0 + c);
            Xt[r][c] = v.x; Xt[r][c+1] = v.y; Xt[r][c+2] = v.z; Xt[r][c+3] = v.w;
        }
        __syncthreads();
        const float* wp = Watt + h0 + g * 16;
#pragma unroll
        for (int h = 0; h < 16; h++) {
            float xv = Xt[sl][g * 16 + h];
#pragma unroll
            for (int a = 0; a < A_; a++) acc[a] += xv * wp[a * H_ + h];
        }
    }
#pragma unroll
    for (int a = 0; a < A_; a++) Pp[a][sl][g] = acc[a];
    __syncthreads();
#pragma unroll
    for (int i = 0; i < 2; i++) {
        int idx = i * 256 + t;
        int a = idx >> 6, s = idx & 63;
        float v = Pp[a][s][0] + Pp[a][s][1] + Pp[a][s][2] + Pp[a][s][3] + batt[a];
        attT[(size_t)b * (S_*A_) + (size_t)(s0 + s) * A_ + a] = v;
    }
}

// ---------------------------------------------------------------------------
// attn2s: inline softmax (from attT) + weighted sum + bf16 hi/lo split.
// Block (b, h-tile 256).  Softmax recomputed per h-tile (cheap, 2 KB).
// ---------------------------------------------------------------------------
__global__ __launch_bounds__(256) void attn2s_kernel(
    const float* __restrict__ x, const float* __restrict__ attT,
    ushort* __restrict__ Ah, ushort* __restrict__ Al)
{
    const int b = blockIdx.x, h0 = blockIdx.y * 256, t = threadIdx.x;
    __shared__ float La[S_ * A_];          // [s][a], 8 KB
    __shared__ float Wsm[A_][260];         // [a][s], 8.1 KB (stride 260: 16B-aligned rows)

    // load logits
#pragma unroll
    for (int i = 0; i < 2; i++) {
        int fid = i * 256 + t;
        *(float4*)&La[fid * 4] =
            *(const float4*)(attT + (size_t)b * (S_*A_) + (size_t)fid * 4);
    }
    __syncthreads();

    // softmax over s per head: 8 heads x 32 lanes
    {
        const int a = t >> 5, l = t & 31;
        float mx = -1e30f;
#pragma unroll
        for (int k = 0; k < 8; k++) mx = fmaxf(mx, La[(l + 32*k) * A_ + a]);
#pragma unroll
        for (int off = 16; off >= 1; off >>= 1) mx = fmaxf(mx, __shfl_xor(mx, off));
        float ev[8]; float sm = 0.f;
#pragma unroll
        for (int k = 0; k < 8; k++) { ev[k] = expf(La[(l + 32*k) * A_ + a] - mx); sm += ev[k]; }
#pragma unroll
        for (int off = 16; off >= 1; off >>= 1) sm += __shfl_xor(sm, off);
        float inv = 1.f / sm;
#pragma unroll
        for (int k = 0; k < 8; k++) Wsm[a][l + 32*k] = ev[k] * inv;
    }
    __syncthreads();

    // weighted sum: thread owns column h0+t
    const float* xb = x + (size_t)b * S_ * H_ + h0 + t;
    float o[A_] = {};
    for (int s0 = 0; s0 < S_; s0 += 4) {
        float xv0 = xb[(size_t)(s0 + 0) * H_];
        float xv1 = xb[(size_t)(s0 + 1) * H_];
        float xv2 = xb[(size_t)(s0 + 2) * H_];
        float xv3 = xb[(size_t)(s0 + 3) * H_];
#pragma unroll
        for (int a = 0; a < A_; a++) {
            float4 w = *(const float4*)&Wsm[a][s0];     // uniform -> LDS broadcast
            o[a] += w.x * xv0 + w.y * xv1 + w.z * xv2 + w.w * xv3;
        }
    }
#pragma unroll
    for (int a = 0; a < A_; a++) {
        float v = o[a];
        ushort hi = f2bf(v);
        ushort lo = f2bf(v - bf2f(hi));
        size_t off = (size_t)(b * 8 + a) * H_ + h0 + t;
        Ah[off] = hi; Al[off] = lo;
    }
}

// ---------------------------------------------------------------------------
// gemm: C = A(512x768) x B^T(8448x768), bf16x3 MFMA (AhBh + AlBh + AhBl).
// B staged from f32 (W_clf / W_enc) and split to hi/lo in-register.
// 128x128 tile, BK=32, 1-barrier double buffer, XOR-swizzled LDS, XCD swizzle.
// ---------------------------------------------------------------------------
__global__ __launch_bounds__(256, 1) void gemm_mfma_kernel(
    const ushort* __restrict__ Ah, const ushort* __restrict__ Al,
    const float* __restrict__ Wclf, const float* __restrict__ Wenc,
    const float* __restrict__ bclf, const float* __restrict__ benc,
    float* __restrict__ c_out, float* __restrict__ emb)
{
    const int f = blockIdx.x;
    const int xcd = f & 7, s = f >> 3;
    const int p = xcd + 8 * (s >> 2);          // B panel 0..65 (+invalid tail)
    const int m = s & 3;
    if (p >= BROWS / 128) return;
    const int n0 = p * 128, m0 = m * 128;

    __shared__ __align__(16) ushort lds[2][4][128 * 32];   // 64 KB
    const int t = threadIdx.x;
    const int w = t >> 6, l = t & 63;
    const int mq = (w & 1) * 64, nq = (w >> 1) * 64;

    const int srow = t >> 2, skc = t & 3;
    const int wr_idx = ((srow * 32 + skc * 8) ^ ((srow & 7) << 3));
    const ushort* baseAh = Ah + (size_t)m0 * H_;
    const ushort* baseAl = Al + (size_t)m0 * H_;
    const float*  baseB  = (n0 < GNUM_) ? (Wclf + (size_t)n0 * H_)
                                        : (Wenc + (size_t)(n0 - GNUM_) * H_);

    uint4  stA[2][2];
    float4 stB[2][2];
    auto loadk = [&](int k0) {
        size_t oA = (size_t)srow * H_ + k0 + skc * 8;
        stA[0][0] = *(const uint4*)(baseAh + oA);
        stA[0][1] = *(const uint4*)(baseAh + oA + (size_t)64 * H_);
        stA[1][0] = *(const uint4*)(baseAl + oA);
        stA[1][1] = *(const uint4*)(baseAl + oA + (size_t)64 * H_);
        const float* bp0 = baseB + (size_t)srow * H_ + k0 + skc * 8;
        const float* bp1 = bp0 + (size_t)64 * H_;
        stB[0][0] = *(const float4*)(bp0);
        stB[0][1] = *(const float4*)(bp0 + 4);
        stB[1][0] = *(const float4*)(bp1);
        stB[1][1] = *(const float4*)(bp1 + 4);
    };

    f32x4 acc[4][4] = {};
    loadk(0);
    const int kc = l >> 4, lr = l & 15;

    for (int kt = 0; kt < H_ / 32; ++kt) {
        ushort* bufp = &lds[kt & 1][0][0];
        // A tiles (pre-split bf16)
#pragma unroll
        for (int xx = 0; xx < 2; xx++) {
            *(uint4*)(bufp + xx * 4096 + wr_idx)        = stA[xx][0];
            *(uint4*)(bufp + xx * 4096 + 2048 + wr_idx) = stA[xx][1];
        }
        // B tile: split f32 -> bf16 hi/lo in-register, then store
#pragma unroll
        for (int rp = 0; rp < 2; rp++) {
            float fv[8] = { stB[rp][0].x, stB[rp][0].y, stB[rp][0].z, stB[rp][0].w,
                            stB[rp][1].x, stB[rp][1].y, stB[rp][1].z, stB[rp][1].w };
            uint4 hi, lo;
            unsigned* hip = (unsigned*)&hi;
            unsigned* lop = (unsigned*)&lo;
#pragma unroll
            for (int j = 0; j < 4; j++) {
                unsigned pk = cvt_pk_bf16(fv[2*j], fv[2*j+1]);
                hip[j] = pk;
                float r0 = fv[2*j]   - asf(pk << 16);
                float r1 = fv[2*j+1] - asf(pk & 0xffff0000u);
                lop[j] = cvt_pk_bf16(r0, r1);
            }
            *(uint4*)(bufp + 2 * 4096 + rp * 2048 + wr_idx) = hi;
            *(uint4*)(bufp + 3 * 4096 + rp * 2048 + wr_idx) = lo;
        }
        __syncthreads();
        if (kt + 1 < H_ / 32) loadk((kt + 1) * 32);

        bf16x8 fah[4], fal[4], fbh[4], fbl[4];
#pragma unroll
        for (int mt = 0; mt < 4; mt++) {
            int r = mq + mt * 16 + lr;
            int idx = ((r * 32 + kc * 8) ^ ((r & 7) << 3));
            fah[mt] = *(const bf16x8*)(bufp + idx);
            fal[mt] = *(const bf16x8*)(bufp + 4096 + idx);
        }
#pragma unroll
        for (int nt = 0; nt < 4; nt++) {
            int r = nq + nt * 16 + lr;
            int idx = ((r * 32 + kc * 8) ^ ((r & 7) << 3));
            fbh[nt] = *(const bf16x8*)(bufp + 2 * 4096 + idx);
            fbl[nt] = *(const bf16x8*)(bufp + 3 * 4096 + idx);
        }
#pragma unroll
        for (int mt = 0; mt < 4; mt++)
#pragma unroll
            for (int nt = 0; nt < 4; nt++) {
                acc[mt][nt] = __builtin_amdgcn_mfma_f32_16x16x32_bf16(fah[mt], fbh[nt], acc[mt][nt], 0, 0, 0);
                acc[mt][nt] = __builtin_amdgcn_mfma_f32_16x16x32_bf16(fal[mt], fbh[nt], acc[mt][nt], 0, 0, 0);
                acc[mt][nt] = __builtin_amdgcn_mfma_f32_16x16x32_bf16(fah[mt], fbl[nt], acc[mt][nt], 0, 0, 0);
            }
    }

    const int q = l >> 4;
    if (n0 < GNUM_) {
#pragma unroll
        for (int mt = 0; mt < 4; mt++)
#pragma unroll
            for (int nt = 0; nt < 4; nt++) {
                f32x4 a = acc[mt][nt];
                float v = fmaxf(fmaxf(a[0], a[1]), fmaxf(a[2], a[3]));
                v = fmaxf(v, __shfl_xor(v, 16));
                if ((q & 1) == 0) {
                    int mg = m0 + mq + mt * 16 + (q >> 1) * 8;
                    int n  = n0 + nq + nt * 16 + lr;
                    c_out[(size_t)(mg >> 3) * GNUM_ + n] = v + bclf[n];
                }
            }
    } else {
#pragma unroll
        for (int mt = 0; mt < 4; mt++)
#pragma unroll
            for (int nt = 0; nt < 4; nt++) {
                int n = n0 - GNUM_ + nq + nt * 16 + lr;
                float bn = benc[n];
#pragma unroll
                for (int r2 = 0; r2 < 4; r2++) {
                    int mg = m0 + mq + mt * 16 + q * 4 + r2;
                    emb[(size_t)mg * E_ + n] = acc[mt][nt][r2] + bn;
                }
            }
    }
}

// ---------------------------------------------------------------------------
// topk: single scan, per-thread register top-10, 10 block-argmax rounds.
// ---------------------------------------------------------------------------
__global__ __launch_bounds__(256) void topk_kernel(
    const float* __restrict__ c_out, const int* __restrict__ gy,
    float* __restrict__ cand_f, float* __restrict__ gcs, int* __restrict__ cand_i)
{
    const int b = blockIdx.x, t = threadIdx.x;
    const int lane = t & 63, wv = t >> 6;
    __shared__ float bvv[4]; __shared__ int bii[4];
    __shared__ float topv[TOPK_]; __shared__ int topi[TOPK_];

    const float* row = c_out + (size_t)b * GNUM_;
    float lv[TOPK_]; int li[TOPK_];
#pragma unroll
    for (int k = 0; k < TOPK_; k++) { lv[k] = -1.f; li[k] = 0x7fffffff; }

    for (int i = t; i < GNUM_; i += 256) {
        float p = 1.f / (1.f + expf(-row[i]));
        if (p > lv[TOPK_ - 1]) {
            float cv = p; int ci = i;
#pragma unroll
            for (int k = 0; k < TOPK_; k++) {
                bool sw = (cv > lv[k]);
                float tv = sw ? lv[k] : cv; int ti = sw ? li[k] : ci;
                lv[k] = sw ? cv : lv[k];    li[k] = sw ? ci : li[k];
                cv = tv; ci = ti;
            }
        }
    }

    for (int rnd = 0; rnd < TOPK_; rnd++) {
        float bv = lv[0]; int bi = li[0];
#pragma unroll
        for (int off = 32; off >= 1; off >>= 1) {
            float ov = __shfl_xor(bv, off); int oi = __shfl_xor(bi, off);
            if (ov > bv || (ov == bv && oi < bi)) { bv = ov; bi = oi; }
        }
        if (lane == 0) { bvv[wv] = bv; bii[wv] = bi; }
        __syncthreads();
        float gbv = bvv[0]; int gbi = bii[0];
#pragma unroll
        for (int w = 1; w < 4; w++) {
            float ov = bvv[w]; int oi = bii[w];
            if (ov > gbv || (ov == gbv && oi < gbi)) { gbv = ov; gbi = oi; }
        }
        if (t == 0) { topv[rnd] = gbv; topi[rnd] = gbi; }
        if (li[0] == gbi) {
#pragma unroll
            for (int k = 0; k < TOPK_ - 1; k++) { lv[k] = lv[k + 1]; li[k] = li[k + 1]; }
            lv[TOPK_ - 1] = -1.f; li[TOPK_ - 1] = 0x7fffffff;
        }
        __syncthreads();
    }

    for (int j = t; j < C_; j += 256) {
        int k = j >> 6, slot = j & 63;
        int gi = topi[k];
        int lbl = gy[gi * GSZ_ + slot];
        cand_f[(size_t)b * C_ + j] = (float)lbl;
        gcs[(size_t)b * C_ + j] = topv[k];
        cand_i[b * C_ + j] = lbl;
    }
}

// ---------------------------------------------------------------------------
// score: l_out[b][c] = max_a dot(embed[cand], emb[b,a,:]).  16 lanes/cand,
// next-candidate row prefetched.
// ---------------------------------------------------------------------------
__global__ __launch_bounds__(256) void score_kernel(
    const float* __restrict__ embw, const float* __restrict__ et,
    const int* __restrict__ cand, float* __restrict__ l_out)
{
    const int b = blockIdx.x, c00 = blockIdx.y * 64, t = threadIdx.x;
    __shared__ float el[A_ * E_];
#pragma unroll
    for (int i = 0; i < 2; i++) {
        int fid = i * 256 + t;
        *(float4*)&el[fid * 4] = *(const float4*)(embw + (size_t)b * (A_*E_) + fid * 4);
    }
    __syncthreads();
    const int lane = t & 63, wv = t >> 6, q = lane >> 4, sub = lane & 15;

    int c = c00 + wv * 4 + q;
    const float* er = et + (size_t)cand[b * C_ + c] * E_ + sub * 4;
    float4 v0 = *(const float4*)(er);
    float4 v1 = *(const float4*)(er + 64);
    float4 v2 = *(const float4*)(er + 128);
    float4 v3 = *(const float4*)(er + 192);

    for (int it = 0; it < 4; it++) {
        float4 n0, n1, n2, n3;
        if (it + 1 < 4) {                       // prefetch next row
            int cn = c00 + (it + 1) * 16 + wv * 4 + q;
            const float* ern = et + (size_t)cand[b * C_ + cn] * E_ + sub * 4;
            n0 = *(const float4*)(ern);
            n1 = *(const float4*)(ern + 64);
            n2 = *(const float4*)(ern + 128);
            n3 = *(const float4*)(ern + 192);
        }
        float best = -1e30f;
#pragma unroll
        for (int a = 0; a < A_; a++) {
            const float* ep = el + a * E_ + sub * 4;
            float4 w0 = *(const float4*)(ep);
            float4 w1 = *(const float4*)(ep + 64);
            float4 w2 = *(const float4*)(ep + 128);
            float4 w3 = *(const float4*)(ep + 192);
            float p = v0.x*w0.x + v0.y*w0.y + v0.z*w0.z + v0.w*w0.w
                    + v1.x*w1.x + v1.y*w1.y + v1.z*w1.z + v1.w*w1.w
                    + v2.x*w2.x + v2.y*w2.y + v2.z*w2.z + v2.w*w2.w
                    + v3.x*w3.x + v3.y*w3.y + v3.z*w3.z + v3.w*w3.w;
#pragma unroll
            for (int off = 8; off >= 1; off >>= 1) p += __shfl_xor(p, off);
            best = fmaxf(best, p);
        }
        if (sub == 0) l_out[(size_t)b * C_ + c00 + it * 16 + wv * 4 + q] = best;
        v0 = n0; v1 = n1; v2 = n2; v3 = n3;
    }
}

// ---------------------------------------------------------------------------
extern "C" void kernel_launch(void* const* d_in, const int* in_sizes, int n_in,
                              void* d_out, int out_size, void* d_ws, size_t ws_size,
                              hipStream_t stream)
{
    (void)in_sizes; (void)n_in; (void)out_size; (void)ws_size;
    const float* x    = (const float*)d_in[0];
    const float* Watt = (const float*)d_in[1];
    const float* batt = (const float*)d_in[2];
    const float* Wclf = (const float*)d_in[3];
    const float* bclf = (const float*)d_in[4];
    const float* Wenc = (const float*)d_in[5];
    const float* benc = (const float*)d_in[6];
    const float* et   = (const float*)d_in[7];
    const int*   gy   = (const int*)d_in[8];

    float* out    = (float*)d_out;
    float* c_out  = out;                        // [64][8192]
    float* l_out  = out + (size_t)B_ * GNUM_;   // [64][640]
    float* cand_f = l_out + (size_t)B_ * C_;    // [64][640]
    float* gcs    = cand_f + (size_t)B_ * C_;   // [64][640]

    char* ws = (char*)d_ws;
    float*  attT  = (float*) (ws);               // 512 KB
    float*  embw  = (float*) (ws + 524288);      // 512 KB
    int*    candi = (int*)   (ws + 1048576);     // 160 KB
    ushort* Ahw   = (ushort*)(ws + 1212416);     // 768 KB
    ushort* Alw   = (ushort*)(ws + 1998848);     // 768 KB

    attn1_kernel<<<dim3(B_, 4), 256, 0, stream>>>(x, Watt, batt, attT);
    attn2s_kernel<<<dim3(B_, 3), 256, 0, stream>>>(x, attT, Ahw, Alw);
    gemm_mfma_kernel<<<288, 256, 0, stream>>>(Ahw, Alw, Wclf, Wenc, bclf, benc, c_out, embw);
    topk_kernel<<<B_, 256, 0, stream>>>(c_out, gy, cand_f, gcs, candi);
    score_kernel<<<dim3(B_, 10), 256, 0, stream>>>(embw, et, candi, l_out);
}